// Round 10
// baseline (85.394 us; speedup 1.0000x reference)
//
#include <hip/hip_runtime.h>
#include <math.h>

#define EPSV 1e-12f

typedef __attribute__((ext_vector_type(8))) short short8;
typedef __attribute__((ext_vector_type(4))) float f32x4;

constexpr int MT    = 10;            // M-tiles of 16 -> K_PAD = 160 class rows
constexpr int K_PAD = MT * 16;
constexpr int CPB   = 32;            // channels per block (2 ct tiles)
constexpr int CG    = 8;             // channel groups (256/32)
constexpr int CHUNK = 128;           // pixels per staged chunk (4 ksteps)
constexpr int PBPX  = 1024;          // pixels per strip
constexpr int NCHK  = PBPX / CHUNK;  // 8 chunks
constexpr int NPB   = 128;           // strips (131072/1024)
constexpr int THR   = 512;           // 8 waves
constexpr int LROW  = 136;           // LDS B-row stride in shorts

// ---------------------------------------------------------------------------
// protomm: segment-sum via one-hot MFMA GEMM.
// grid = NPB*CG = 1024 blocks (4 blocks/CU -> r8-proven TLP), CPB=32 keeps
// partial at 21 MB (r7 traffic). Wave (ct=w&1, par=w>>1) owns m=par+4j,
// full K -> complete accumulators. Flush staged via LDS -> full-line stores.
// ---------------------------------------------------------------------------
__global__ __launch_bounds__(THR, 8) void protomm_kernel(
    const float* __restrict__ feat,     // [B,C,HW]
    const int*   __restrict__ labels,   // [B,HW]
    const int*   __restrict__ ign_p,
    float*       __restrict__ partial,  // [NPB][K_PAD][C]
    float*       __restrict__ vmask,    // [K_PAD] pre-zeroed
    int C, int HW)
{
    __shared__ unsigned short Bf[2][CPB * LROW];   // 17.4 KB
    __shared__ int   labL[PBPX];                   // 4 KB
    __shared__ float ftile[4][16][36];             // 9.2 KB
    __shared__ unsigned char pres[K_PAD];

    const int tid   = threadIdx.x;
    const int w     = tid >> 6;
    const int l     = tid & 63;
    const int ct    = w & 1;            // channel tile (16 ch)
    const int par   = w >> 1;           // 0..3, m = par + 4j
    const int rowid = l & 15;
    const int g     = l >> 4;

    const int bid = blockIdx.x;
    const int cg  = bid & 7;
    const int pb  = bid >> 3;           // 0..127
    const int b   = pb >> 4;            // image
    const int px0 = (pb & 15) * PBPX;
    const int ig  = *ign_p;

    const int qq  = tid & 31;
    const int chp = tid >> 5;           // 0..15
    const float* fb = feat + ((size_t)(b * C + cg * CPB + chp)) * HW + px0 + 4 * qq;
    const int*   lb = labels + (size_t)b * HW + px0;

    // preload labels for the whole strip; init presence
    if (cg == 0)
        for (int i = tid; i < K_PAD; i += THR) pres[i] = 0;
    #pragma unroll
    for (int i = 0; i < PBPX / THR; ++i) {
        int lv = lb[tid + i * THR];
        labL[tid + i * THR] = (lv == ig) ? 0 : lv;
    }
    __syncthreads();
    if (cg == 0) {
        #pragma unroll
        for (int i = 0; i < PBPX / THR; ++i) {
            int la = labL[tid + i * THR];
            if ((unsigned)la < (unsigned)K_PAD) pres[la] = 1;  // benign races
        }
    }

    f32x4 acc[3];
    #pragma unroll
    for (int j = 0; j < 3; ++j) acc[j] = (f32x4){0.f, 0.f, 0.f, 0.f};

    float4 xa0, xa1, xb0, xb1;
    auto issueA = [&](int ck) {
        const float* p = fb + ck * CHUNK;
        xa0 = *reinterpret_cast<const float4*>(p);
        xa1 = *reinterpret_cast<const float4*>(p + (size_t)16 * HW);
    };
    auto issueB = [&](int ck) {
        const float* p = fb + ck * CHUNK;
        xb0 = *reinterpret_cast<const float4*>(p);
        xb1 = *reinterpret_cast<const float4*>(p + (size_t)16 * HW);
    };
    auto commit = [&](int buf, float4 v0, float4 v1) {
        unsigned p0, p1, p2, p3;
        asm("v_cvt_pk_bf16_f32 %0, %1, %2" : "=v"(p0) : "v"(v0.x), "v"(v0.y));
        asm("v_cvt_pk_bf16_f32 %0, %1, %2" : "=v"(p1) : "v"(v0.z), "v"(v0.w));
        asm("v_cvt_pk_bf16_f32 %0, %1, %2" : "=v"(p2) : "v"(v1.x), "v"(v1.y));
        asm("v_cvt_pk_bf16_f32 %0, %1, %2" : "=v"(p3) : "v"(v1.z), "v"(v1.w));
        *reinterpret_cast<uint2*>(&Bf[buf][chp * LROW + 4 * qq])        = make_uint2(p0, p1);
        *reinterpret_cast<uint2*>(&Bf[buf][(chp + 16) * LROW + 4 * qq]) = make_uint2(p2, p3);
    };
    auto CONSUME = [&](int buf, int ck) {
        #pragma unroll
        for (int ks = 0; ks < 4; ++ks) {
            const int4 lA = *reinterpret_cast<const int4*>(&labL[ck * CHUNK + ks * 32 + g * 8]);
            const int4 lB = *reinterpret_cast<const int4*>(&labL[ck * CHUNK + ks * 32 + g * 8 + 4]);
            const short8 bfrag = *reinterpret_cast<const short8*>(
                &Bf[buf][(ct * 16 + rowid) * LROW + ks * 32 + g * 8]);
            #pragma unroll
            for (int j = 0; j < 3; ++j) {
                const int m = par + 4 * j;
                if (m < MT) {
                    const int tgt = m * 16 + rowid;
                    unsigned a0 = (lA.x == tgt ? 0x3F80u : 0u) | (lA.y == tgt ? 0x3F800000u : 0u);
                    unsigned a1 = (lA.z == tgt ? 0x3F80u : 0u) | (lA.w == tgt ? 0x3F800000u : 0u);
                    unsigned a2 = (lB.x == tgt ? 0x3F80u : 0u) | (lB.y == tgt ? 0x3F800000u : 0u);
                    unsigned a3 = (lB.z == tgt ? 0x3F80u : 0u) | (lB.w == tgt ? 0x3F800000u : 0u);
                    uint4 aw = make_uint4(a0, a1, a2, a3);
                    short8 afrag = __builtin_bit_cast(short8, aw);
                    acc[j] = __builtin_amdgcn_mfma_f32_16x16x32_bf16(afrag, bfrag, acc[j], 0, 0, 0);
                }
            }
        }
    };

    issueA(0);
    #pragma unroll 1
    for (int it = 0; it < NCHK / 2; ++it) {
        const int ck = 2 * it;
        issueB(ck + 1);                       // in flight across commitA's wait
        commit(0, xa0, xa1);
        __syncthreads();
        CONSUME(0, ck);
        if (ck + 2 < NCHK) issueA(ck + 2);    // in flight across commitB's wait
        commit(1, xb0, xb1);
        __syncthreads();
        CONSUME(1, ck + 1);
    }

    // flush: stage (par-tile) x 16 x 32 in LDS, store full 128B lines
    __syncthreads();
    #pragma unroll 1
    for (int j = 0; j < 3; ++j) {
        const int m = par + 4 * j;
        if (m < MT) {
            #pragma unroll
            for (int r = 0; r < 4; ++r)
                ftile[par][g * 4 + r][ct * 16 + rowid] = acc[j][r];
        }
        __syncthreads();
        {
            const int par2 = tid >> 7, row = (tid >> 3) & 15, cq = tid & 7;
            const int m2 = par2 + 4 * j;
            if (m2 < MT) {
                float4 v = *reinterpret_cast<const float4*>(&ftile[par2][row][4 * cq]);
                *reinterpret_cast<float4*>(
                    partial + (size_t)pb * K_PAD * C + (size_t)(m2 * 16 + row) * C
                            + cg * CPB + 4 * cq) = v;
            }
        }
        __syncthreads();
    }

    if (cg == 0)
        for (int i = tid; i < K_PAD; i += THR)
            if (pres[i]) vmask[i] = 1.0f;
}

// ---------------------------------------------------------------------------
// tail: block k. Phase 1: float4 reduce of partial row k over NPB=128 slots
// (8 chains) + L2-normalize (count-divide cancels). Phase 2: text sweep,
// float4 loads, fused text-norm + online logsumexp. Ticket finalize.
// ---------------------------------------------------------------------------
__global__ __launch_bounds__(256) void tail_kernel(
    const float* __restrict__ partial,    // [NPB][K_PAD][C]
    const float* __restrict__ text,       // [K][C]
    const float* __restrict__ vmask,      // [K_PAD]
    float* __restrict__ loss_acc,
    unsigned int* __restrict__ ticket,
    float* __restrict__ out,
    int K, int C, int nblocks)
{
    __shared__ float ph[256];
    __shared__ float scr[4][260];
    __shared__ float vm[K_PAD];
    __shared__ float red[5];
    __shared__ float wred[12];
    __shared__ unsigned int lastflag;

    const int k    = blockIdx.x;
    const int tid  = threadIdx.x;
    const int wid  = tid >> 6;
    const int lane = tid & 63;

    if (tid < K_PAD) vm[tid] = vmask[tid];
    __syncthreads();
    const bool valid = (vm[k] > 0.f);

    float contrib = 0.f;
    if (valid) {
        const int cq = tid & 63;
        const int sg = tid >> 6;
        const size_t gs = (size_t)K_PAD * C;
        const float* pbase = partial + (size_t)k * C + 4 * cq;
        float4 a0 = {0,0,0,0}, a1 = {0,0,0,0}, a2 = {0,0,0,0}, a3 = {0,0,0,0};
        float4 a4 = {0,0,0,0}, a5 = {0,0,0,0}, a6 = {0,0,0,0}, a7 = {0,0,0,0};
        for (int o = 0; o < NPB; o += 32) {
            a0 += *(const float4*)(pbase + (size_t)(o + sg +  0) * gs);
            a1 += *(const float4*)(pbase + (size_t)(o + sg +  4) * gs);
            a2 += *(const float4*)(pbase + (size_t)(o + sg +  8) * gs);
            a3 += *(const float4*)(pbase + (size_t)(o + sg + 12) * gs);
            a4 += *(const float4*)(pbase + (size_t)(o + sg + 16) * gs);
            a5 += *(const float4*)(pbase + (size_t)(o + sg + 20) * gs);
            a6 += *(const float4*)(pbase + (size_t)(o + sg + 24) * gs);
            a7 += *(const float4*)(pbase + (size_t)(o + sg + 28) * gs);
        }
        float4 asum = (((a0 + a1) + (a2 + a3)) + ((a4 + a5) + (a6 + a7)));
        *(float4*)&scr[sg][4 * cq] = asum;
        __syncthreads();
        float val = scr[0][tid] + scr[1][tid] + scr[2][tid] + scr[3][tid];

        float v = val * val;
        #pragma unroll
        for (int o = 32; o > 0; o >>= 1) v += __shfl_down(v, o);
        if (lane == 0) red[wid] = v;
        __syncthreads();
        if (tid == 0) {
            float s = red[0] + red[1] + red[2] + red[3];
            red[4] = 1.0f / fmaxf(sqrtf(s), EPSV);
        }
        __syncthreads();
        ph[tid] = val * red[4];
        __syncthreads();

        const float4 pv = *(const float4*)&ph[4 * lane];
        float m = -INFINITY, s = 0.f, skk = 0.f;
        #pragma unroll 1
        for (int gq = 0; gq < K_PAD / 16; ++gq) {
            const int j0 = gq * 16 + wid * 4;
            const float4* t0 = (const float4*)(text + (size_t)(j0 + 0 < K ? j0 + 0 : 0) * C);
            const float4* t1 = (const float4*)(text + (size_t)(j0 + 1 < K ? j0 + 1 : 0) * C);
            const float4* t2 = (const float4*)(text + (size_t)(j0 + 2 < K ? j0 + 2 : 0) * C);
            const float4* t3 = (const float4*)(text + (size_t)(j0 + 3 < K ? j0 + 3 : 0) * C);
            float4 x0 = t0[lane], x1 = t1[lane], x2 = t2[lane], x3 = t3[lane];
            float d0 = pv.x*x0.x + pv.y*x0.y + pv.z*x0.z + pv.w*x0.w;
            float q0 = x0.x*x0.x + x0.y*x0.y + x0.z*x0.z + x0.w*x0.w;
            float d1 = pv.x*x1.x + pv.y*x1.y + pv.z*x1.z + pv.w*x1.w;
            float q1 = x1.x*x1.x + x1.y*x1.y + x1.z*x1.z + x1.w*x1.w;
            float d2 = pv.x*x2.x + pv.y*x2.y + pv.z*x2.z + pv.w*x2.w;
            float q2 = x2.x*x2.x + x2.y*x2.y + x2.z*x2.z + x2.w*x2.w;
            float d3 = pv.x*x3.x + pv.y*x3.y + pv.z*x3.z + pv.w*x3.w;
            float q3 = x3.x*x3.x + x3.y*x3.y + x3.z*x3.z + x3.w*x3.w;
            #pragma unroll
            for (int o = 32; o > 0; o >>= 1) {
                d0 += __shfl_down(d0, o); d1 += __shfl_down(d1, o);
                d2 += __shfl_down(d2, o); d3 += __shfl_down(d3, o);
                q0 += __shfl_down(q0, o); q1 += __shfl_down(q1, o);
                q2 += __shfl_down(q2, o); q3 += __shfl_down(q3, o);
            }
            if (lane == 0) {
                float dd[4] = {d0, d1, d2, d3};
                float qq[4] = {q0, q1, q2, q3};
                #pragma unroll
                for (int r = 0; r < 4; ++r) {
                    int j = j0 + r;
                    float vmj = vm[j];
                    float sim = dd[r] * (10.0f / fmaxf(sqrtf(qq[r]), EPSV));
                    float ms  = vmj * sim - (1.f - vmj) * 1e9f;
                    if (j == k) skk = ms;
                    if (ms > m) { s = s * __expf(m - ms) + 1.f; m = ms; }
                    else        { s += __expf(ms - m); }
                }
            }
        }
        if (lane == 0) { wred[wid*3+0] = m; wred[wid*3+1] = s; wred[wid*3+2] = skk; }
        __syncthreads();
        if (tid == 0) {
            float M = fmaxf(fmaxf(wred[0], wred[3]), fmaxf(wred[6], wred[9]));
            float S = 0.f, SKK = 0.f;
            #pragma unroll
            for (int ww = 0; ww < 4; ++ww) {
                S   += wred[ww*3+1] * __expf(wred[ww*3+0] - M);
                SKK += wred[ww*3+2];
            }
            contrib = M + logf(S) - SKK;      // -logp[k][k]
        }
    }

    if (tid == 0) {
        if (valid) atomicAdd(loss_acc, contrib);
        __threadfence();
        unsigned old = atomicAdd(ticket, 1u);
        lastflag = (old == (unsigned)(nblocks - 1)) ? 1u : 0u;
    }
    __syncthreads();
    if (lastflag) {
        float v = (tid < K_PAD) ? vm[tid] : 0.f;
        #pragma unroll
        for (int o = 32; o > 0; o >>= 1) v += __shfl_down(v, o);
        if (lane == 0) red[wid] = v;
        __syncthreads();
        if (tid == 0) {
            float nv = red[0] + red[1] + red[2] + red[3];
            float total = atomicAdd(loss_acc, 0.0f);   // device-scope read
            out[0] = (nv > 1.f) ? total / fmaxf(nv, 1.f) : 0.f;
        }
    }
}

extern "C" void kernel_launch(void* const* d_in, const int* in_sizes, int n_in,
                              void* d_out, int out_size, void* d_ws, size_t ws_size,
                              hipStream_t stream) {
    const float* feat   = (const float*)d_in[0];
    const int*   labels = (const int*)d_in[1];
    const float* text   = (const float*)d_in[2];
    const int*   ign    = (const int*)d_in[3];

    const int B  = 8;
    const int N  = in_sizes[1];          // 131072
    const int HW = N / B;                // 16384
    const int C  = in_sizes[0] / N;      // 256
    const int K  = in_sizes[2] / C;      // 150

    // workspace: partial [NPB][K_PAD][C] (~21 MB, fully overwritten) | vmask | acc | ticket
    float*        partial  = (float*)d_ws;
    float*        vmask    = partial + (size_t)NPB * K_PAD * C;
    float*        loss_acc = vmask + K_PAD;
    unsigned int* ticket   = (unsigned int*)(loss_acc + 1);

    hipMemsetAsync(vmask, 0, (K_PAD + 2) * sizeof(float), stream);

    protomm_kernel<<<NPB * CG, THR, 0, stream>>>(
        feat, labels, ign, partial, vmask, C, HW);

    tail_kernel<<<K, 256, 0, stream>>>(
        partial, text, vmask, loss_acc, ticket, (float*)d_out, K, C, K);
}

// Round 11
// 71.380 us; speedup vs baseline: 1.1963x; 1.1963x over previous
//
#include <hip/hip_runtime.h>
#include <math.h>

#define EPSV 1e-12f

typedef __attribute__((ext_vector_type(8))) short short8;
typedef __attribute__((ext_vector_type(4))) float f32x4;

constexpr int MT    = 10;            // m-tiles of 16 -> K_PAD = 160
constexpr int K_PAD = 160;
constexpr int CPB   = 64;            // channels per block (4 ct tiles)
constexpr int CHPX  = 64;            // pixels per chunk (2 ksteps)
constexpr int PBPX  = 1024;          // pixels per strip
constexpr int NCHK  = PBPX / CHPX;   // 16 chunks
constexpr int NPB   = 128;           // strips
constexpr int THR   = 512;           // 8 waves

// ---------------------------------------------------------------------------
// protomm: one-hot MFMA GEMM with 4-deep global_load_lds pipeline.
// Chunk = 64ch x 64px f32 staged raw into LDS (16 KB), XOR-swizzled slots
// (slot = ch*16 + (p4 ^ (ch&7))) via pre-swizzled GLOBAL source (both-sides
// rule). Counted vmcnt(4) + raw s_barrier per chunk keeps 3 chunks in
// flight. Wave (ctg=w&1, mg=w>>1): A-frag built once per m, used for 2 ct.
// ---------------------------------------------------------------------------
__global__ __launch_bounds__(THR, 4) void protomm_kernel(
    const float* __restrict__ feat,     // [B,C,HW]
    const int*   __restrict__ labels,   // [B,HW]
    const int*   __restrict__ ign_p,
    float*       __restrict__ partial,  // [NPB][K_PAD][C]
    float*       __restrict__ vmask,    // [K_PAD] pre-zeroed
    int C, int HW)
{
    __shared__ float stage[4][4096];        // 64 KB (4 bufs x 1024 slots x 16B)
    __shared__ int   labL[PBPX];            // 4 KB
    __shared__ unsigned char pres[K_PAD];

    const int tid   = threadIdx.x;
    const int w     = tid >> 6;
    const int lane  = tid & 63;
    const int rowid = lane & 15;
    const int g     = lane >> 4;
    const int ctg   = w & 1;            // ct pair {2ctg, 2ctg+1}
    const int mg    = w >> 1;           // m in {mg, mg+4, mg+8<10}

    const int bid = blockIdx.x;
    const int cg  = bid & 3;
    const int pb  = bid >> 2;
    const int b   = pb >> 4;
    const int px0 = (pb & 15) * PBPX;
    const int ig  = *ign_p;

    if (cg == 0)
        for (int i = tid; i < K_PAD; i += THR) pres[i] = 0;
    {
        int l0 = labels[(size_t)b * HW + px0 + tid];
        int l1 = labels[(size_t)b * HW + px0 + THR + tid];
        labL[tid]       = (l0 == ig) ? 0 : l0;
        labL[tid + THR] = (l1 == ig) ? 0 : l1;
    }
    __syncthreads();
    if (cg == 0) {
        int la = labL[tid];
        if ((unsigned)la < (unsigned)K_PAD) pres[la] = 1;
        la = labL[tid + THR];
        if ((unsigned)la < (unsigned)K_PAD) pres[la] = 1;
    }

    // loader mapping: thread t owns slots t and t+512; slot s -> ch=s>>4,
    // p4 = (s&15) ^ (ch&7)  (inverse-swizzled global source, linear LDS)
    const int sch = tid >> 4;                       // 0..31
    const int p40 = (tid & 15) ^ (sch & 7);
    const float* gb0 = feat + ((size_t)(b * C + cg * CPB + sch)) * HW + px0 + 4 * p40;
    const float* gb1 = gb0 + (size_t)32 * HW;       // ch+32 has same (ch&7)

    auto ISSUE = [&](int ck) {
        const int buf = ck & 3;
        __builtin_amdgcn_global_load_lds(
            (const __attribute__((address_space(1))) void*)(gb0 + ck * CHPX),
            (__attribute__((address_space(3))) void*)&stage[buf][tid * 4], 16, 0, 0);
        __builtin_amdgcn_global_load_lds(
            (const __attribute__((address_space(1))) void*)(gb1 + ck * CHPX),
            (__attribute__((address_space(3))) void*)&stage[buf][tid * 4 + 2048], 16, 0, 0);
    };

    f32x4 acc0[3], acc1[3];
    #pragma unroll
    for (int j = 0; j < 3; ++j) {
        acc0[j] = (f32x4){0.f, 0.f, 0.f, 0.f};
        acc1[j] = (f32x4){0.f, 0.f, 0.f, 0.f};
    }

    auto CONSUME = [&](int ck) {
        const int buf = ck & 3;
        #pragma unroll
        for (int ks = 0; ks < 2; ++ks) {
            const int pxb = ck * CHPX + ks * 32 + g * 8;
            const int4 lA = *reinterpret_cast<const int4*>(&labL[pxb]);
            const int4 lB = *reinterpret_cast<const int4*>(&labL[pxb + 4]);
            const int px4 = ks * 8 + g * 2;
            short8 bfr0, bfr1;
            {
                const int ch = ctg * 32 + rowid;
                const int x  = ch & 7;
                const float4 f0 = *reinterpret_cast<const float4*>(
                    &stage[buf][(ch * 16 + (px4 ^ x)) * 4]);
                const float4 f1 = *reinterpret_cast<const float4*>(
                    &stage[buf][(ch * 16 + ((px4 + 1) ^ x)) * 4]);
                unsigned q0, q1, q2, q3;
                asm("v_cvt_pk_bf16_f32 %0, %1, %2" : "=v"(q0) : "v"(f0.x), "v"(f0.y));
                asm("v_cvt_pk_bf16_f32 %0, %1, %2" : "=v"(q1) : "v"(f0.z), "v"(f0.w));
                asm("v_cvt_pk_bf16_f32 %0, %1, %2" : "=v"(q2) : "v"(f1.x), "v"(f1.y));
                asm("v_cvt_pk_bf16_f32 %0, %1, %2" : "=v"(q3) : "v"(f1.z), "v"(f1.w));
                bfr0 = __builtin_bit_cast(short8, make_uint4(q0, q1, q2, q3));
            }
            {
                const int ch = ctg * 32 + 16 + rowid;
                const int x  = ch & 7;
                const float4 f0 = *reinterpret_cast<const float4*>(
                    &stage[buf][(ch * 16 + (px4 ^ x)) * 4]);
                const float4 f1 = *reinterpret_cast<const float4*>(
                    &stage[buf][(ch * 16 + ((px4 + 1) ^ x)) * 4]);
                unsigned q0, q1, q2, q3;
                asm("v_cvt_pk_bf16_f32 %0, %1, %2" : "=v"(q0) : "v"(f0.x), "v"(f0.y));
                asm("v_cvt_pk_bf16_f32 %0, %1, %2" : "=v"(q1) : "v"(f0.z), "v"(f0.w));
                asm("v_cvt_pk_bf16_f32 %0, %1, %2" : "=v"(q2) : "v"(f1.x), "v"(f1.y));
                asm("v_cvt_pk_bf16_f32 %0, %1, %2" : "=v"(q3) : "v"(f1.z), "v"(f1.w));
                bfr1 = __builtin_bit_cast(short8, make_uint4(q0, q1, q2, q3));
            }
            #pragma unroll
            for (int j = 0; j < 3; ++j) {
                const int m = mg + 4 * j;
                if (m < MT) {
                    const int tgt = m * 16 + rowid;
                    unsigned a0 = (lA.x == tgt ? 0x3F80u : 0u) | (lA.y == tgt ? 0x3F800000u : 0u);
                    unsigned a1 = (lA.z == tgt ? 0x3F80u : 0u) | (lA.w == tgt ? 0x3F800000u : 0u);
                    unsigned a2 = (lB.x == tgt ? 0x3F80u : 0u) | (lB.y == tgt ? 0x3F800000u : 0u);
                    unsigned a3 = (lB.z == tgt ? 0x3F80u : 0u) | (lB.w == tgt ? 0x3F800000u : 0u);
                    short8 afrag = __builtin_bit_cast(short8, make_uint4(a0, a1, a2, a3));
                    acc0[j] = __builtin_amdgcn_mfma_f32_16x16x32_bf16(afrag, bfr0, acc0[j], 0, 0, 0);
                    acc1[j] = __builtin_amdgcn_mfma_f32_16x16x32_bf16(afrag, bfr1, acc1[j], 0, 0, 0);
                }
            }
        }
    };

    ISSUE(0); ISSUE(1); ISSUE(2);
    #pragma unroll 1
    for (int ck = 0; ck < NCHK - 2; ++ck) {
        asm volatile("s_waitcnt vmcnt(4)" ::: "memory");   // chunk ck arrived
        __builtin_amdgcn_sched_barrier(0);
        __builtin_amdgcn_s_barrier();                      // raw: no vmcnt drain
        __builtin_amdgcn_sched_barrier(0);
        if (ck + 3 < NCHK) ISSUE(ck + 3);                  // into buf (ck-1)&3: safe
        CONSUME(ck);
    }
    asm volatile("s_waitcnt vmcnt(2)" ::: "memory");
    __builtin_amdgcn_sched_barrier(0);
    __builtin_amdgcn_s_barrier();
    __builtin_amdgcn_sched_barrier(0);
    CONSUME(NCHK - 2);
    asm volatile("s_waitcnt vmcnt(0)" ::: "memory");
    __builtin_amdgcn_sched_barrier(0);
    __builtin_amdgcn_s_barrier();
    __builtin_amdgcn_sched_barrier(0);
    CONSUME(NCHK - 1);

    // flush: each wave owns (m-set x 2 ct) fully; r7-proven 64B-segment stores
    {
        float* dst = partial + (size_t)pb * K_PAD * C + cg * CPB;
        #pragma unroll
        for (int j = 0; j < 3; ++j) {
            const int m = mg + 4 * j;
            if (m < MT) {
                #pragma unroll
                for (int c2 = 0; c2 < 2; ++c2) {
                    const int col = (ctg * 2 + c2) * 16 + rowid;
                    #pragma unroll
                    for (int r = 0; r < 4; ++r) {
                        const int cls = m * 16 + g * 4 + r;
                        dst[(size_t)cls * C + col] = (c2 == 0) ? acc0[j][r] : acc1[j][r];
                    }
                }
            }
        }
    }
    if (cg == 0) {
        __syncthreads();
        for (int i = tid; i < K_PAD; i += THR)
            if (pres[i]) vmask[i] = 1.0f;
    }
}

// ---------------------------------------------------------------------------
// tail: block k. Phase 1: float4 reduce of partial row k over NPB slots +
// L2-normalize (count cancels). Phase 2: text sweep, fused norm + online
// logsumexp. Ticket finalize.
// ---------------------------------------------------------------------------
__global__ __launch_bounds__(256) void tail_kernel(
    const float* __restrict__ partial,    // [NPB][K_PAD][C]
    const float* __restrict__ text,       // [K][C]
    const float* __restrict__ vmask,      // [K_PAD]
    float* __restrict__ loss_acc,
    unsigned int* __restrict__ ticket,
    float* __restrict__ out,
    int K, int C, int nblocks)
{
    __shared__ float ph[256];
    __shared__ float scr[4][260];
    __shared__ float vm[K_PAD];
    __shared__ float red[5];
    __shared__ float wred[12];
    __shared__ unsigned int lastflag;

    const int k    = blockIdx.x;
    const int tid  = threadIdx.x;
    const int wid  = tid >> 6;
    const int lane = tid & 63;

    if (tid < K_PAD) vm[tid] = vmask[tid];
    __syncthreads();
    const bool valid = (vm[k] > 0.f);

    float contrib = 0.f;
    if (valid) {
        const int cq = tid & 63;
        const int sg = tid >> 6;
        const size_t gs = (size_t)K_PAD * C;
        const float* pbase = partial + (size_t)k * C + 4 * cq;
        float4 a0 = {0,0,0,0}, a1 = {0,0,0,0}, a2 = {0,0,0,0}, a3 = {0,0,0,0};
        float4 a4 = {0,0,0,0}, a5 = {0,0,0,0}, a6 = {0,0,0,0}, a7 = {0,0,0,0};
        for (int o = 0; o < NPB; o += 32) {
            a0 += *(const float4*)(pbase + (size_t)(o + sg +  0) * gs);
            a1 += *(const float4*)(pbase + (size_t)(o + sg +  4) * gs);
            a2 += *(const float4*)(pbase + (size_t)(o + sg +  8) * gs);
            a3 += *(const float4*)(pbase + (size_t)(o + sg + 12) * gs);
            a4 += *(const float4*)(pbase + (size_t)(o + sg + 16) * gs);
            a5 += *(const float4*)(pbase + (size_t)(o + sg + 20) * gs);
            a6 += *(const float4*)(pbase + (size_t)(o + sg + 24) * gs);
            a7 += *(const float4*)(pbase + (size_t)(o + sg + 28) * gs);
        }
        float4 asum = (((a0 + a1) + (a2 + a3)) + ((a4 + a5) + (a6 + a7)));
        *(float4*)&scr[sg][4 * cq] = asum;
        __syncthreads();
        float val = scr[0][tid] + scr[1][tid] + scr[2][tid] + scr[3][tid];

        float v = val * val;
        #pragma unroll
        for (int o = 32; o > 0; o >>= 1) v += __shfl_down(v, o);
        if (lane == 0) red[wid] = v;
        __syncthreads();
        if (tid == 0) {
            float s = red[0] + red[1] + red[2] + red[3];
            red[4] = 1.0f / fmaxf(sqrtf(s), EPSV);
        }
        __syncthreads();
        ph[tid] = val * red[4];
        __syncthreads();

        const float4 pv = *(const float4*)&ph[4 * lane];
        float m = -INFINITY, s = 0.f, skk = 0.f;
        #pragma unroll 1
        for (int gq = 0; gq < K_PAD / 16; ++gq) {
            const int j0 = gq * 16 + wid * 4;
            const float4* t0 = (const float4*)(text + (size_t)(j0 + 0 < K ? j0 + 0 : 0) * C);
            const float4* t1 = (const float4*)(text + (size_t)(j0 + 1 < K ? j0 + 1 : 0) * C);
            const float4* t2 = (const float4*)(text + (size_t)(j0 + 2 < K ? j0 + 2 : 0) * C);
            const float4* t3 = (const float4*)(text + (size_t)(j0 + 3 < K ? j0 + 3 : 0) * C);
            float4 x0 = t0[lane], x1 = t1[lane], x2 = t2[lane], x3 = t3[lane];
            float d0 = pv.x*x0.x + pv.y*x0.y + pv.z*x0.z + pv.w*x0.w;
            float q0 = x0.x*x0.x + x0.y*x0.y + x0.z*x0.z + x0.w*x0.w;
            float d1 = pv.x*x1.x + pv.y*x1.y + pv.z*x1.z + pv.w*x1.w;
            float q1 = x1.x*x1.x + x1.y*x1.y + x1.z*x1.z + x1.w*x1.w;
            float d2 = pv.x*x2.x + pv.y*x2.y + pv.z*x2.z + pv.w*x2.w;
            float q2 = x2.x*x2.x + x2.y*x2.y + x2.z*x2.z + x2.w*x2.w;
            float d3 = pv.x*x3.x + pv.y*x3.y + pv.z*x3.z + pv.w*x3.w;
            float q3 = x3.x*x3.x + x3.y*x3.y + x3.z*x3.z + x3.w*x3.w;
            #pragma unroll
            for (int o = 32; o > 0; o >>= 1) {
                d0 += __shfl_down(d0, o); d1 += __shfl_down(d1, o);
                d2 += __shfl_down(d2, o); d3 += __shfl_down(d3, o);
                q0 += __shfl_down(q0, o); q1 += __shfl_down(q1, o);
                q2 += __shfl_down(q2, o); q3 += __shfl_down(q3, o);
            }
            if (lane == 0) {
                float dd[4] = {d0, d1, d2, d3};
                float qq[4] = {q0, q1, q2, q3};
                #pragma unroll
                for (int r = 0; r < 4; ++r) {
                    int j = j0 + r;
                    float vmj = vm[j];
                    float sim = dd[r] * (10.0f / fmaxf(sqrtf(qq[r]), EPSV));
                    float ms  = vmj * sim - (1.f - vmj) * 1e9f;
                    if (j == k) skk = ms;
                    if (ms > m) { s = s * __expf(m - ms) + 1.f; m = ms; }
                    else        { s += __expf(ms - m); }
                }
            }
        }
        if (lane == 0) { wred[wid*3+0] = m; wred[wid*3+1] = s; wred[wid*3+2] = skk; }
        __syncthreads();
        if (tid == 0) {
            float M = fmaxf(fmaxf(wred[0], wred[3]), fmaxf(wred[6], wred[9]));
            float S = 0.f, SKK = 0.f;
            #pragma unroll
            for (int ww = 0; ww < 4; ++ww) {
                S   += wred[ww*3+1] * __expf(wred[ww*3+0] - M);
                SKK += wred[ww*3+2];
            }
            contrib = M + logf(S) - SKK;      // -logp[k][k]
        }
    }

    if (tid == 0) {
        if (valid) atomicAdd(loss_acc, contrib);
        __threadfence();
        unsigned old = atomicAdd(ticket, 1u);
        lastflag = (old == (unsigned)(nblocks - 1)) ? 1u : 0u;
    }
    __syncthreads();
    if (lastflag) {
        float v = (tid < K_PAD) ? vm[tid] : 0.f;
        #pragma unroll
        for (int o = 32; o > 0; o >>= 1) v += __shfl_down(v, o);
        if (lane == 0) red[wid] = v;
        __syncthreads();
        if (tid == 0) {
            float nv = red[0] + red[1] + red[2] + red[3];
            float total = atomicAdd(loss_acc, 0.0f);   // device-scope read
            out[0] = (nv > 1.f) ? total / fmaxf(nv, 1.f) : 0.f;
        }
    }
}

extern "C" void kernel_launch(void* const* d_in, const int* in_sizes, int n_in,
                              void* d_out, int out_size, void* d_ws, size_t ws_size,
                              hipStream_t stream) {
    const float* feat   = (const float*)d_in[0];
    const int*   labels = (const int*)d_in[1];
    const float* text   = (const float*)d_in[2];
    const int*   ign    = (const int*)d_in[3];

    const int B  = 8;
    const int N  = in_sizes[1];          // 131072
    const int HW = N / B;                // 16384
    const int C  = in_sizes[0] / N;      // 256
    const int K  = in_sizes[2] / C;      // 150

    float*        partial  = (float*)d_ws;                 // [NPB][K_PAD][C] ~21 MB
    float*        vmask    = partial + (size_t)NPB * K_PAD * C;
    float*        loss_acc = vmask + K_PAD;
    unsigned int* ticket   = (unsigned int*)(loss_acc + 1);

    hipMemsetAsync(vmask, 0, (K_PAD + 2) * sizeof(float), stream);

    protomm_kernel<<<NPB * 4, THR, 0, stream>>>(
        feat, labels, ign, partial, vmask, C, HW);

    tail_kernel<<<K, 256, 0, stream>>>(
        partial, text, vmask, loss_acc, ticket, (float*)d_out, K, C, K);
}

// Round 12
// 70.974 us; speedup vs baseline: 1.2032x; 1.0057x over previous
//
#include <hip/hip_runtime.h>
#include <math.h>

#define EPSV 1e-12f

typedef __attribute__((ext_vector_type(8))) short short8;
typedef __attribute__((ext_vector_type(4))) float f32x4;

constexpr int MT    = 10;            // m-tiles of 16 -> K_PAD = 160
constexpr int K_PAD = 160;
constexpr int CPB   = 32;            // channels per block (2 ct tiles)
constexpr int CG    = 8;             // channel groups
constexpr int CHPX  = 64;            // pixels per chunk (2 ksteps)
constexpr int PBPX  = 1024;          // pixels per strip
constexpr int NCHK  = PBPX / CHPX;   // 16 chunks
constexpr int NPB   = 128;           // strips
constexpr int THR   = 512;           // 8 waves

// ---------------------------------------------------------------------------
// protomm: one-hot MFMA GEMM, 4-deep global_load_lds pipeline, 4 blocks/CU.
// Chunk = 32ch x 64px f32 (8 KB) staged into LDS with XOR-swizzled slots
// (slot = ch*16 + (p4 ^ (ch&7))) via inverse-swizzled GLOBAL source.
// Counted vmcnt keeps 3 chunks in flight across raw s_barriers.
// partial is BLOCK-PRIVATE: [pb][cg][K_PAD][CPB] -> flush is one linear
// 20 KB LDS->global copy (full-line writes, no amplification).
// ---------------------------------------------------------------------------
__global__ __launch_bounds__(THR, 8) void protomm_kernel(
    const float* __restrict__ feat,     // [B,C,HW]
    const int*   __restrict__ labels,   // [B,HW]
    const int*   __restrict__ ign_p,
    float*       __restrict__ partial,  // [NPB][CG][K_PAD][CPB]
    float*       __restrict__ vmask,    // [K_PAD] pre-zeroed
    int C, int HW)
{
    __shared__ float stage[4][2048];        // 32 KB (4 bufs x 8 KB)
    __shared__ int   labL[PBPX];            // 4 KB
    __shared__ unsigned char pres[K_PAD];

    const int tid   = threadIdx.x;
    const int w     = tid >> 6;
    const int lane  = tid & 63;
    const int rowid = lane & 15;
    const int g     = lane >> 4;
    const int ct    = w & 1;            // channel tile (16 ch)
    const int mg    = w >> 1;           // m in {mg, mg+4, mg+8<10}

    const int bid = blockIdx.x;
    const int cg  = bid & 7;
    const int pb  = bid >> 3;
    const int b   = pb >> 4;
    const int px0 = (pb & 15) * PBPX;
    const int ig  = *ign_p;

    if (cg == 0)
        for (int i = tid; i < K_PAD; i += THR) pres[i] = 0;
    {
        int l0 = labels[(size_t)b * HW + px0 + tid];
        int l1 = labels[(size_t)b * HW + px0 + THR + tid];
        labL[tid]       = (l0 == ig) ? 0 : l0;
        labL[tid + THR] = (l1 == ig) ? 0 : l1;
    }
    __syncthreads();
    if (cg == 0) {
        int la = labL[tid];
        if ((unsigned)la < (unsigned)K_PAD) pres[la] = 1;
        la = labL[tid + THR];
        if ((unsigned)la < (unsigned)K_PAD) pres[la] = 1;
    }

    // loader: thread t owns slot t; slot s -> ch = s>>4, p4 = (s&15)^(ch&7)
    const int sch = tid >> 4;                       // 0..31
    const int p40 = (tid & 15) ^ (sch & 7);
    const float* gb = feat + ((size_t)(b * C + cg * CPB + sch)) * HW + px0 + 4 * p40;

    auto ISSUE = [&](int ck) {
        const int buf = ck & 3;
        __builtin_amdgcn_global_load_lds(
            (const __attribute__((address_space(1))) void*)(gb + ck * CHPX),
            (__attribute__((address_space(3))) void*)&stage[buf][tid * 4], 16, 0, 0);
    };

    f32x4 acc[3];
    #pragma unroll
    for (int j = 0; j < 3; ++j) acc[j] = (f32x4){0.f, 0.f, 0.f, 0.f};

    auto CONSUME = [&](int ck) {
        const int buf = ck & 3;
        #pragma unroll
        for (int ks = 0; ks < 2; ++ks) {
            const int pxb = ck * CHPX + ks * 32 + g * 8;
            const int4 lA = *reinterpret_cast<const int4*>(&labL[pxb]);
            const int4 lB = *reinterpret_cast<const int4*>(&labL[pxb + 4]);
            const int px4 = ks * 8 + g * 2;
            const int ch  = ct * 16 + rowid;
            const int x   = ch & 7;
            const float4 f0 = *reinterpret_cast<const float4*>(
                &stage[buf][(ch * 16 + (px4 ^ x)) * 4]);
            const float4 f1 = *reinterpret_cast<const float4*>(
                &stage[buf][(ch * 16 + ((px4 + 1) ^ x)) * 4]);
            unsigned q0, q1, q2, q3;
            asm("v_cvt_pk_bf16_f32 %0, %1, %2" : "=v"(q0) : "v"(f0.x), "v"(f0.y));
            asm("v_cvt_pk_bf16_f32 %0, %1, %2" : "=v"(q1) : "v"(f0.z), "v"(f0.w));
            asm("v_cvt_pk_bf16_f32 %0, %1, %2" : "=v"(q2) : "v"(f1.x), "v"(f1.y));
            asm("v_cvt_pk_bf16_f32 %0, %1, %2" : "=v"(q3) : "v"(f1.z), "v"(f1.w));
            const short8 bfrag = __builtin_bit_cast(short8, make_uint4(q0, q1, q2, q3));
            #pragma unroll
            for (int j = 0; j < 3; ++j) {
                const int m = mg + 4 * j;
                if (m < MT) {
                    const int tgt = m * 16 + rowid;
                    unsigned a0 = (lA.x == tgt ? 0x3F80u : 0u) | (lA.y == tgt ? 0x3F800000u : 0u);
                    unsigned a1 = (lA.z == tgt ? 0x3F80u : 0u) | (lA.w == tgt ? 0x3F800000u : 0u);
                    unsigned a2 = (lB.x == tgt ? 0x3F80u : 0u) | (lB.y == tgt ? 0x3F800000u : 0u);
                    unsigned a3 = (lB.z == tgt ? 0x3F80u : 0u) | (lB.w == tgt ? 0x3F800000u : 0u);
                    short8 afrag = __builtin_bit_cast(short8, make_uint4(a0, a1, a2, a3));
                    acc[j] = __builtin_amdgcn_mfma_f32_16x16x32_bf16(afrag, bfrag, acc[j], 0, 0, 0);
                }
            }
        }
    };

    ISSUE(0); ISSUE(1); ISSUE(2);
    #pragma unroll 1
    for (int ck = 0; ck < NCHK - 2; ++ck) {
        asm volatile("s_waitcnt vmcnt(2) lgkmcnt(0)" ::: "memory");  // chunk ck in LDS
        __builtin_amdgcn_sched_barrier(0);
        __builtin_amdgcn_s_barrier();                 // raw: prefetches stay in flight
        __builtin_amdgcn_sched_barrier(0);
        if (ck + 3 < NCHK) ISSUE(ck + 3);
        CONSUME(ck);
    }
    asm volatile("s_waitcnt vmcnt(1) lgkmcnt(0)" ::: "memory");
    __builtin_amdgcn_sched_barrier(0);
    __builtin_amdgcn_s_barrier();
    __builtin_amdgcn_sched_barrier(0);
    CONSUME(NCHK - 2);
    asm volatile("s_waitcnt vmcnt(0) lgkmcnt(0)" ::: "memory");
    __builtin_amdgcn_sched_barrier(0);
    __builtin_amdgcn_s_barrier();
    __builtin_amdgcn_sched_barrier(0);
    CONSUME(NCHK - 1);

    // flush: park acc in stage (reused as [K_PAD][CPB] f32), then one linear
    // 20 KB LDS->global copy into the block-private slab.
    __syncthreads();                    // everyone done reading stage
    {
        float* ftile = &stage[0][0];    // 5120 floats = 20 KB
        #pragma unroll
        for (int j = 0; j < 3; ++j) {
            const int m = mg + 4 * j;
            if (m < MT) {
                #pragma unroll
                for (int r = 0; r < 4; ++r)
                    ftile[(m * 16 + g * 4 + r) * CPB + ct * 16 + rowid] = acc[j][r];
            }
        }
    }
    __syncthreads();
    {
        const float4* src = reinterpret_cast<const float4*>(&stage[0][0]);
        float4* dst = reinterpret_cast<float4*>(
            partial + ((size_t)pb * CG + cg) * (size_t)K_PAD * CPB);
        #pragma unroll
        for (int i = 0; i < (K_PAD * CPB / 4 + THR - 1) / THR; ++i) {
            int idx = tid + i * THR;
            if (idx < K_PAD * CPB / 4) dst[idx] = src[idx];
        }
    }
    if (cg == 0) {
        for (int i = tid; i < K_PAD; i += THR)
            if (pres[i]) vmask[i] = 1.0f;
    }
}

// ---------------------------------------------------------------------------
// tail: block k. Phase 1: float4 reduce over NPB=128 slots (8 chains) in the
// block-private layout + L2-normalize (count cancels). Phase 2: text sweep,
// fused norm + online logsumexp. Ticket finalize.
// ---------------------------------------------------------------------------
__global__ __launch_bounds__(256) void tail_kernel(
    const float* __restrict__ partial,    // [NPB][CG][K_PAD][CPB]
    const float* __restrict__ text,       // [K][C]
    const float* __restrict__ vmask,      // [K_PAD]
    float* __restrict__ loss_acc,
    unsigned int* __restrict__ ticket,
    float* __restrict__ out,
    int K, int C, int nblocks)
{
    __shared__ float ph[256];
    __shared__ float scr[4][260];
    __shared__ float vm[K_PAD];
    __shared__ float red[5];
    __shared__ float wred[12];
    __shared__ unsigned int lastflag;

    const int k    = blockIdx.x;
    const int tid  = threadIdx.x;
    const int wid  = tid >> 6;
    const int lane = tid & 63;

    if (tid < K_PAD) vm[tid] = vmask[tid];
    __syncthreads();
    const bool valid = (vm[k] > 0.f);

    float contrib = 0.f;
    if (valid) {
        // phase 1: thread (sg = tid>>6, cq = tid&63); cq -> (cg = cq>>3, q = cq&7)
        const int cq = tid & 63;
        const int sg = tid >> 6;
        const size_t gs = (size_t)CG * K_PAD * CPB;     // slot stride
        const float* pbase = partial
            + ((size_t)(cq >> 3) * K_PAD + k) * CPB + 4 * (cq & 7);
        float4 a0 = {0,0,0,0}, a1 = {0,0,0,0}, a2 = {0,0,0,0}, a3 = {0,0,0,0};
        float4 a4 = {0,0,0,0}, a5 = {0,0,0,0}, a6 = {0,0,0,0}, a7 = {0,0,0,0};
        for (int o = 0; o < NPB; o += 32) {
            a0 += *(const float4*)(pbase + (size_t)(o + sg +  0) * gs);
            a1 += *(const float4*)(pbase + (size_t)(o + sg +  4) * gs);
            a2 += *(const float4*)(pbase + (size_t)(o + sg +  8) * gs);
            a3 += *(const float4*)(pbase + (size_t)(o + sg + 12) * gs);
            a4 += *(const float4*)(pbase + (size_t)(o + sg + 16) * gs);
            a5 += *(const float4*)(pbase + (size_t)(o + sg + 20) * gs);
            a6 += *(const float4*)(pbase + (size_t)(o + sg + 24) * gs);
            a7 += *(const float4*)(pbase + (size_t)(o + sg + 28) * gs);
        }
        float4 asum = (((a0 + a1) + (a2 + a3)) + ((a4 + a5) + (a6 + a7)));
        *(float4*)&scr[sg][4 * cq] = asum;
        __syncthreads();
        float val = scr[0][tid] + scr[1][tid] + scr[2][tid] + scr[3][tid];

        float v = val * val;
        #pragma unroll
        for (int o = 32; o > 0; o >>= 1) v += __shfl_down(v, o);
        if (lane == 0) red[wid] = v;
        __syncthreads();
        if (tid == 0) {
            float s = red[0] + red[1] + red[2] + red[3];
            red[4] = 1.0f / fmaxf(sqrtf(s), EPSV);
        }
        __syncthreads();
        ph[tid] = val * red[4];
        __syncthreads();

        const float4 pv = *(const float4*)&ph[4 * lane];
        float m = -INFINITY, s = 0.f, skk = 0.f;
        #pragma unroll 1
        for (int gq = 0; gq < K_PAD / 16; ++gq) {
            const int j0 = gq * 16 + wid * 4;
            const float4* t0 = (const float4*)(text + (size_t)(j0 + 0 < K ? j0 + 0 : 0) * C);
            const float4* t1 = (const float4*)(text + (size_t)(j0 + 1 < K ? j0 + 1 : 0) * C);
            const float4* t2 = (const float4*)(text + (size_t)(j0 + 2 < K ? j0 + 2 : 0) * C);
            const float4* t3 = (const float4*)(text + (size_t)(j0 + 3 < K ? j0 + 3 : 0) * C);
            float4 x0 = t0[lane], x1 = t1[lane], x2 = t2[lane], x3 = t3[lane];
            float d0 = pv.x*x0.x + pv.y*x0.y + pv.z*x0.z + pv.w*x0.w;
            float q0 = x0.x*x0.x + x0.y*x0.y + x0.z*x0.z + x0.w*x0.w;
            float d1 = pv.x*x1.x + pv.y*x1.y + pv.z*x1.z + pv.w*x1.w;
            float q1 = x1.x*x1.x + x1.y*x1.y + x1.z*x1.z + x1.w*x1.w;
            float d2 = pv.x*x2.x + pv.y*x2.y + pv.z*x2.z + pv.w*x2.w;
            float q2 = x2.x*x2.x + x2.y*x2.y + x2.z*x2.z + x2.w*x2.w;
            float d3 = pv.x*x3.x + pv.y*x3.y + pv.z*x3.z + pv.w*x3.w;
            float q3 = x3.x*x3.x + x3.y*x3.y + x3.z*x3.z + x3.w*x3.w;
            #pragma unroll
            for (int o = 32; o > 0; o >>= 1) {
                d0 += __shfl_down(d0, o); d1 += __shfl_down(d1, o);
                d2 += __shfl_down(d2, o); d3 += __shfl_down(d3, o);
                q0 += __shfl_down(q0, o); q1 += __shfl_down(q1, o);
                q2 += __shfl_down(q2, o); q3 += __shfl_down(q3, o);
            }
            if (lane == 0) {
                float dd[4] = {d0, d1, d2, d3};
                float qq[4] = {q0, q1, q2, q3};
                #pragma unroll
                for (int r = 0; r < 4; ++r) {
                    int j = j0 + r;
                    float vmj = vm[j];
                    float sim = dd[r] * (10.0f / fmaxf(sqrtf(qq[r]), EPSV));
                    float ms  = vmj * sim - (1.f - vmj) * 1e9f;
                    if (j == k) skk = ms;
                    if (ms > m) { s = s * __expf(m - ms) + 1.f; m = ms; }
                    else        { s += __expf(ms - m); }
                }
            }
        }
        if (lane == 0) { wred[wid*3+0] = m; wred[wid*3+1] = s; wred[wid*3+2] = skk; }
        __syncthreads();
        if (tid == 0) {
            float M = fmaxf(fmaxf(wred[0], wred[3]), fmaxf(wred[6], wred[9]));
            float S = 0.f, SKK = 0.f;
            #pragma unroll
            for (int ww = 0; ww < 4; ++ww) {
                S   += wred[ww*3+1] * __expf(wred[ww*3+0] - M);
                SKK += wred[ww*3+2];
            }
            contrib = M + logf(S) - SKK;      // -logp[k][k]
        }
    }

    if (tid == 0) {
        if (valid) atomicAdd(loss_acc, contrib);
        __threadfence();
        unsigned old = atomicAdd(ticket, 1u);
        lastflag = (old == (unsigned)(nblocks - 1)) ? 1u : 0u;
    }
    __syncthreads();
    if (lastflag) {
        float v = (tid < K_PAD) ? vm[tid] : 0.f;
        #pragma unroll
        for (int o = 32; o > 0; o >>= 1) v += __shfl_down(v, o);
        if (lane == 0) red[wid] = v;
        __syncthreads();
        if (tid == 0) {
            float nv = red[0] + red[1] + red[2] + red[3];
            float total = atomicAdd(loss_acc, 0.0f);   // device-scope read
            out[0] = (nv > 1.f) ? total / fmaxf(nv, 1.f) : 0.f;
        }
    }
}

extern "C" void kernel_launch(void* const* d_in, const int* in_sizes, int n_in,
                              void* d_out, int out_size, void* d_ws, size_t ws_size,
                              hipStream_t stream) {
    const float* feat   = (const float*)d_in[0];
    const int*   labels = (const int*)d_in[1];
    const float* text   = (const float*)d_in[2];
    const int*   ign    = (const int*)d_in[3];

    const int B  = 8;
    const int N  = in_sizes[1];          // 131072
    const int HW = N / B;                // 16384
    const int C  = in_sizes[0] / N;      // 256
    const int K  = in_sizes[2] / C;      // 150

    float*        partial  = (float*)d_ws;   // [NPB][CG][K_PAD][CPB] ~21 MB
    float*        vmask    = partial + (size_t)NPB * CG * K_PAD * CPB;
    float*        loss_acc = vmask + K_PAD;
    unsigned int* ticket   = (unsigned int*)(loss_acc + 1);

    hipMemsetAsync(vmask, 0, (K_PAD + 2) * sizeof(float), stream);

    protomm_kernel<<<NPB * CG, THR, 0, stream>>>(
        feat, labels, ign, partial, vmask, C, HW);

    tail_kernel<<<K, 256, 0, stream>>>(
        partial, text, vmask, loss_acc, ticket, (float*)d_out, K, C, K);
}